// Round 1
// baseline (2473.753 us; speedup 1.0000x reference)
//
#include <hip/hip_runtime.h>
#include <hip/hip_bf16.h>

#define Bb 256
#define Tt 128
#define Cc 141
#define Dd 1536
#define Hh 141
#define Gg 564
#define Gp 576
#define K2 288
#define NY 320
#define MM (Bb*Cc)   // 36096

typedef float f32x4 __attribute__((ext_vector_type(4)));
typedef short s16x8 __attribute__((ext_vector_type(8)));
typedef _Float16 h2 __attribute__((ext_vector_type(2)));

__device__ __forceinline__ short f2bf(float f){
    union { float f; unsigned u; } v; v.f = f;
    unsigned r = v.u + 0x7fffu + ((v.u >> 16) & 1u);
    return (short)(r >> 16);
}
__device__ __forceinline__ float bf2f(short s){
    union { unsigned u; float f; } v; v.u = ((unsigned)(unsigned short)s) << 16;
    return v.f;
}
__device__ __forceinline__ float fdot2(h2 a, h2 b, float c){
#if __has_builtin(__builtin_amdgcn_fdot2)
    return __builtin_amdgcn_fdot2(a, b, c, false);
#else
    return c + (float)a.x * (float)b.x + (float)a.y * (float)b.y;
#endif
}
__device__ __forceinline__ float sigm(float x){ return 1.f / (1.f + __expf(-x)); }
__device__ __forceinline__ float tanh_(float x){ float e = __expf(2.f * x); return 1.f - 2.f / (e + 1.f); }

// ---------------- weight convert f32 -> bf16 with zero padding -------------
__global__ __launch_bounds__(256) void convert_pad(const float* __restrict__ src,
                                                   short* __restrict__ dst,
                                                   int R, int Kin, int Rp, int Kp){
    int idx = blockIdx.x * 256 + threadIdx.x;
    if (idx >= Rp * Kp) return;
    int r = idx / Kp, k = idx - r * Kp;
    float v = (r < R && k < Kin) ? src[(size_t)r * Kin + k] : 0.f;
    dst[idx] = f2bf(v);
}

// ---------------- char gather index ----------------------------------------
__global__ __launch_bounds__(256) void build_gather(const int* __restrict__ offm,
                                                    int* __restrict__ gidx){
    int m = blockIdx.x * 256 + threadIdx.x;
    if (m >= MM) return;
    int b = m / Cc, c = m - b * Cc;
    int found = -1;
    for (int t = 0; t < Tt; t++){
        int s = offm[((size_t)(b * Tt + t)) * 2];
        int e = offm[((size_t)(b * Tt + t)) * 2 + 1];
        if (s <= c && c < e){ found = b * Tt + t; break; }
    }
    gidx[m] = found;
}

// ---------------- GEMM: C[M,N](bf16) = A[M,K] @ B[N,K]^T + bias ------------
// BM=128, BN=64, BK=32; 256 threads (4 waves, 2x2), wave tile 64x32.
// GATHER: A is f32 tok_feats indirected through gidx (neg -> zero row).
template<bool GATHER>
__global__ __launch_bounds__(256, 2) void gemm_bt(const void* __restrict__ Av,
                                                  const short* __restrict__ Bw,
                                                  const float* __restrict__ bias, int Nbias,
                                                  short* __restrict__ Cout,
                                                  const int* __restrict__ gidx,
                                                  int N, int K, int ldc){
    const int m0 = blockIdx.x * 128, n0 = blockIdx.y * 64;
    const int tid = threadIdx.x, lane = tid & 63, wid = tid >> 6;
    const int wm = wid >> 1, wn = wid & 1;
    __shared__ short As[128][40];
    __shared__ short Bs[64][40];
    f32x4 acc[4][2] = {};

    for (int k0 = 0; k0 < K; k0 += 32){
        // stage A (128 x 32)
        if (!GATHER){
            const short* A = (const short*)Av;
            #pragma unroll
            for (int i = 0; i < 2; i++){
                int e = tid + i * 256;
                int row = e >> 2, c8 = e & 3;
                uint4 v = *(const uint4*)(A + (size_t)(m0 + row) * K + k0 + c8 * 8);
                *(uint4*)&As[row][c8 * 8] = v;
            }
        } else {
            const float* A = (const float*)Av;
            #pragma unroll
            for (int i = 0; i < 2; i++){
                int e = tid + i * 256;
                int row = e >> 2, c8 = e & 3;
                int g = gidx[m0 + row];
                uint4 pk = make_uint4(0u, 0u, 0u, 0u);
                if (g >= 0){
                    const float* src = A + (size_t)g * K + k0 + c8 * 8;
                    unsigned w0 = (unsigned short)f2bf(src[0]) | ((unsigned)(unsigned short)f2bf(src[1]) << 16);
                    unsigned w1 = (unsigned short)f2bf(src[2]) | ((unsigned)(unsigned short)f2bf(src[3]) << 16);
                    unsigned w2_ = (unsigned short)f2bf(src[4]) | ((unsigned)(unsigned short)f2bf(src[5]) << 16);
                    unsigned w3 = (unsigned short)f2bf(src[6]) | ((unsigned)(unsigned short)f2bf(src[7]) << 16);
                    pk = make_uint4(w0, w1, w2_, w3);
                }
                *(uint4*)&As[row][c8 * 8] = pk;
            }
        }
        // stage B (64 x 32)
        {
            int row = tid >> 2, c8 = tid & 3;
            uint4 v = *(const uint4*)(Bw + (size_t)(n0 + row) * K + k0 + c8 * 8);
            *(uint4*)&Bs[row][c8 * 8] = v;
        }
        __syncthreads();

        const int kq = (lane >> 4) * 8, r16 = lane & 15;
        s16x8 af[4], bf[2];
        #pragma unroll
        for (int mt = 0; mt < 4; mt++) af[mt] = *(const s16x8*)&As[wm * 64 + mt * 16 + r16][kq];
        #pragma unroll
        for (int nt = 0; nt < 2; nt++) bf[nt] = *(const s16x8*)&Bs[wn * 32 + nt * 16 + r16][kq];
        #pragma unroll
        for (int mt = 0; mt < 4; mt++)
            #pragma unroll
            for (int nt = 0; nt < 2; nt++)
                acc[mt][nt] = __builtin_amdgcn_mfma_f32_16x16x32_bf16(af[mt], bf[nt], acc[mt][nt], 0, 0, 0);
        __syncthreads();
    }

    // epilogue: bias + store bf16
    #pragma unroll
    for (int nt = 0; nt < 2; nt++){
        int col = n0 + wn * 32 + nt * 16 + (lane & 15);
        float bv = (col < Nbias) ? bias[col] : 0.f;
        #pragma unroll
        for (int mt = 0; mt < 4; mt++){
            int rowbase = m0 + wm * 64 + mt * 16 + (lane >> 4) * 4;
            #pragma unroll
            for (int r = 0; r < 4; r++){
                int row = rowbase + r;
                float v = acc[mt][nt][r] + bv;
                if (GATHER && gidx[row] < 0) v = 0.f;
                Cout[(size_t)row * ldc + col] = f2bf(v);
            }
        }
    }
}

// ---------------- LSTM scan: one (batch, dir) per block --------------------
// 576 threads: thread j owns gate row j (w_hh row in 71 packed-f16 VGPRs).
// h broadcast via LDS; 141 steps; writes layer output (bf16) + hn/cn (f32).
__global__ __launch_bounds__(576) void lstm_scan(const short* __restrict__ xW_f,
                                                 const short* __restrict__ xW_b,
                                                 const float* __restrict__ whh_f,
                                                 const float* __restrict__ whh_b,
                                                 const float* __restrict__ h0l,
                                                 const float* __restrict__ c0l,
                                                 short* __restrict__ xout,
                                                 float* __restrict__ hnl,
                                                 float* __restrict__ cnl){
    const int dir = blockIdx.x & 1;
    const int b = blockIdx.x >> 1;
    const int j = threadIdx.x;
    const short* xW = dir ? xW_b : xW_f;
    const float* whh = dir ? whh_b : whh_f;

    __shared__ float pre[Gg];
    __shared__ h2 hsh[72];

    h2 wreg[71];
    if (j < Gg){
        const float* wr = whh + (size_t)j * Hh;
        #pragma unroll
        for (int kk = 0; kk < 70; kk++){
            h2 w; w.x = (_Float16)wr[2 * kk]; w.y = (_Float16)wr[2 * kk + 1];
            wreg[kk] = w;
        }
        h2 w; w.x = (_Float16)wr[140]; w.y = (_Float16)0.f;
        wreg[70] = w;
    }

    float hcur = 0.f, ccur = 0.f;
    if (j < Hh){
        hcur = h0l[(size_t)dir * Bb * Hh + b * Hh + j];
        ccur = c0l[(size_t)dir * Bb * Hh + b * Hh + j];
    }
    if (j < 144) ((_Float16*)hsh)[j] = (j < Hh) ? (_Float16)hcur : (_Float16)0.f;
    __syncthreads();

    for (int t = 0; t < Cc; t++){
        int tt = dir ? (Cc - 1 - t) : t;
        if (j < Gg){
            float xw = bf2f(xW[((size_t)b * Cc + tt) * Gp + j]);
            float acc0 = 0.f, acc1 = 0.f;
            #pragma unroll
            for (int kk = 0; kk < 71; kk++){
                if (kk & 1) acc1 = fdot2(wreg[kk], hsh[kk], acc1);
                else        acc0 = fdot2(wreg[kk], hsh[kk], acc0);
            }
            pre[j] = xw + acc0 + acc1;
        }
        __syncthreads();
        if (j < Hh){
            float gi = sigm(pre[j]);
            float gf = sigm(pre[j + Hh]);
            float gg = tanh_(pre[j + 2 * Hh]);
            float go = sigm(pre[j + 3 * Hh]);
            ccur = gf * ccur + gi * gg;
            hcur = go * tanh_(ccur);
            xout[((size_t)b * Cc + tt) * K2 + dir * Hh + j] = f2bf(hcur);
            ((_Float16*)hsh)[j] = (_Float16)hcur;
        }
        __syncthreads();
    }
    if (j < Hh){
        hnl[(size_t)dir * Bb * Hh + b * Hh + j] = hcur;
        cnl[(size_t)dir * Bb * Hh + b * Hh + j] = ccur;
    }
}

// ---------------- head2: y2 = y1 @ w2^T + b2; split outputs ---------------
__global__ __launch_bounds__(256) void head2_k(const short* __restrict__ y1,
                                               const float* __restrict__ w2,
                                               const float* __restrict__ b2,
                                               float* __restrict__ X1,
                                               float* __restrict__ X2){
    int m = blockIdx.x * 256 + threadIdx.x;
    if (m >= MM) return;
    float a0 = b2[0], a1 = b2[1];
    for (int k = 0; k < 282; k++){
        float v = bf2f(y1[(size_t)m * NY + k]);
        a0 += v * w2[k];
        a1 += v * w2[282 + k];
    }
    X1[m] = a0;
    X2[m] = a1;
}

extern "C" void kernel_launch(void* const* d_in, const int* in_sizes, int n_in,
                              void* d_out, int out_size, void* d_ws, size_t ws_size,
                              hipStream_t stream){
    const float* tok     = (const float*)d_in[0];
    const int*   offm    = (const int*)d_in[1];
    const float* h0      = (const float*)d_in[2];
    const float* c0      = (const float*)d_in[3];
    const float* w_lin   = (const float*)d_in[4];
    const float* b_lin   = (const float*)d_in[5];
    const float* w_ih0_f = (const float*)d_in[6];
    const float* w_ih0_b = (const float*)d_in[7];
    const float* w_ih_f  = (const float*)d_in[8];
    const float* w_ih_b  = (const float*)d_in[9];
    const float* w_hh_f  = (const float*)d_in[10];
    const float* w_hh_b  = (const float*)d_in[11];
    const float* b_f     = (const float*)d_in[12];
    const float* b_b     = (const float*)d_in[13];
    const float* w1      = (const float*)d_in[14];
    const float* b1      = (const float*)d_in[15];
    const float* w2      = (const float*)d_in[16];
    const float* b2      = (const float*)d_in[17];

    float* out = (float*)d_out;
    float* oX1 = out;
    float* oX2 = out + MM;
    float* ohn = out + 2 * MM;
    float* ocn = ohn + 8 * Bb * Hh;

    char* ws = (char*)d_ws;
    size_t off = 0;
    auto alloc = [&](size_t bytes) -> void* {
        void* p = ws + off;
        off += (bytes + 255) & ~(size_t)255;
        return p;
    };
    short* x0      = (short*)alloc((size_t)MM * Dd * 2);
    short* wlin16  = (short*)alloc((size_t)Dd * Dd * 2);
    short* wih0f   = (short*)alloc((size_t)Gp * Dd * 2);
    short* wih0b   = (short*)alloc((size_t)Gp * Dd * 2);
    short* wihf123 = (short*)alloc((size_t)3 * Gp * K2 * 2);
    short* wihb123 = (short*)alloc((size_t)3 * Gp * K2 * 2);
    short* w1p     = (short*)alloc((size_t)NY * K2 * 2);
    int*   gidx    = (int*)alloc((size_t)MM * 4);
    short* xWf     = (short*)alloc((size_t)MM * Gp * 2);
    short* xWb     = (short*)alloc((size_t)MM * Gp * 2);
    short* xA      = (short*)alloc((size_t)MM * K2 * 2);
    short* xB      = (short*)alloc((size_t)MM * K2 * 2);
    short* y1      = xWf;  // alias: xW dead when head runs

    auto cdiv = [](int a, int b){ return (a + b - 1) / b; };

    // weight conversions
    convert_pad<<<cdiv(Dd * Dd, 256), 256, 0, stream>>>(w_lin, wlin16, Dd, Dd, Dd, Dd);
    convert_pad<<<cdiv(Gp * Dd, 256), 256, 0, stream>>>(w_ih0_f, wih0f, Gg, Dd, Gp, Dd);
    convert_pad<<<cdiv(Gp * Dd, 256), 256, 0, stream>>>(w_ih0_b, wih0b, Gg, Dd, Gp, Dd);
    for (int l = 1; l < 4; l++){
        convert_pad<<<cdiv(Gp * K2, 256), 256, 0, stream>>>(w_ih_f + (size_t)(l - 1) * Gg * 282,
                                                            wihf123 + (size_t)(l - 1) * Gp * K2,
                                                            Gg, 282, Gp, K2);
        convert_pad<<<cdiv(Gp * K2, 256), 256, 0, stream>>>(w_ih_b + (size_t)(l - 1) * Gg * 282,
                                                            wihb123 + (size_t)(l - 1) * Gp * K2,
                                                            Gg, 282, Gp, K2);
    }
    convert_pad<<<cdiv(NY * K2, 256), 256, 0, stream>>>(w1, w1p, 282, 282, NY, K2);

    build_gather<<<cdiv(MM, 256), 256, 0, stream>>>(offm, gidx);
    hipMemsetAsync(xA, 0, (size_t)MM * K2 * 2, stream);
    hipMemsetAsync(xB, 0, (size_t)MM * K2 * 2, stream);

    // fused linear + char scatter: x0[m,:] = tok[gidx[m],:] @ w_lin^T + b_lin (or 0)
    gemm_bt<true><<<dim3(MM / 128, Dd / 64), 256, 0, stream>>>(tok, wlin16, b_lin, Dd, x0, gidx, Dd, Dd, Dd);

    const short* xin = x0;
    int Kl = Dd;
    short* outbuf[4] = { xA, xB, xA, xB };
    for (int l = 0; l < 4; l++){
        const short* wf = (l == 0) ? wih0f : wihf123 + (size_t)(l - 1) * Gp * K2;
        const short* wb = (l == 0) ? wih0b : wihb123 + (size_t)(l - 1) * Gp * K2;
        gemm_bt<false><<<dim3(MM / 128, Gp / 64), 256, 0, stream>>>(xin, wf, b_f + (size_t)l * Gg, Gg, xWf, nullptr, Gp, Kl, Gp);
        gemm_bt<false><<<dim3(MM / 128, Gp / 64), 256, 0, stream>>>(xin, wb, b_b + (size_t)l * Gg, Gg, xWb, nullptr, Gp, Kl, Gp);
        lstm_scan<<<512, 576, 0, stream>>>(xWf, xWb,
                                           w_hh_f + (size_t)l * Gg * Hh, w_hh_b + (size_t)l * Gg * Hh,
                                           h0 + (size_t)(2 * l) * Bb * Hh, c0 + (size_t)(2 * l) * Bb * Hh,
                                           outbuf[l],
                                           ohn + (size_t)(2 * l) * Bb * Hh, ocn + (size_t)(2 * l) * Bb * Hh);
        xin = outbuf[l];
        Kl = K2;
    }

    // head: y1 = x4 @ w1^T + b1 (bf16), then tiny second layer
    gemm_bt<false><<<dim3(MM / 128, NY / 64), 256, 0, stream>>>(xin, w1p, b1, 282, y1, nullptr, NY, K2, NY);
    head2_k<<<cdiv(MM, 256), 256, 0, stream>>>(y1, w2, b2, oX1, oX2);
}

// Round 3
// 2036.022 us; speedup vs baseline: 1.2150x; 1.2150x over previous
//
#include <hip/hip_runtime.h>
#include <hip/hip_bf16.h>

#define Bb 256
#define Tt 128
#define Cc 141
#define Dd 1536
#define Hh 141
#define Gg 564
#define Gp 576
#define Nc 1152      // combined f+b gate columns (2*Gp)
#define K2p 320      // padded layer input width for layers 1-3
#define MM (Bb*Cc)   // 36096

typedef float f32x4 __attribute__((ext_vector_type(4)));
typedef short s16x8 __attribute__((ext_vector_type(8)));
typedef _Float16 h2 __attribute__((ext_vector_type(2)));

typedef __attribute__((address_space(1))) const void GvT;
typedef __attribute__((address_space(3))) void LvT;
#define GLOAD16(g, l) __builtin_amdgcn_global_load_lds((GvT*)(g), (LvT*)(l), 16, 0, 0)

__device__ __forceinline__ short f2bf(float f){
    union { float f; unsigned u; } v; v.f = f;
    unsigned r = v.u + 0x7fffu + ((v.u >> 16) & 1u);
    return (short)(r >> 16);
}
__device__ __forceinline__ float bf2f(short s){
    union { unsigned u; float f; } v; v.u = ((unsigned)(unsigned short)s) << 16;
    return v.f;
}
__device__ __forceinline__ float fdot2(h2 a, h2 b, float c){
#if __has_builtin(__builtin_amdgcn_fdot2)
    return __builtin_amdgcn_fdot2(a, b, c, false);
#else
    return c + (float)a.x * (float)b.x + (float)a.y * (float)b.y;
#endif
}
__device__ __forceinline__ float sigm(float x){ return 1.f / (1.f + __expf(-x)); }
__device__ __forceinline__ float tanh_(float x){ float e = __expf(2.f * x); return 1.f - 2.f / (e + 1.f); }

// ---------------- weight convert f32 -> bf16 with zero padding -------------
__global__ __launch_bounds__(256) void convert_pad(const float* __restrict__ src,
                                                   short* __restrict__ dst,
                                                   int R, int Kin, int Rp, int Kp){
    int idx = blockIdx.x * 256 + threadIdx.x;
    if (idx >= Rp * Kp) return;
    int r = idx / Kp, k = idx - r * Kp;
    float v = (r < R && k < Kin) ? src[(size_t)r * Kin + k] : 0.f;
    dst[idx] = f2bf(v);
}

// ---------------- char gather index ----------------------------------------
__global__ __launch_bounds__(256) void build_gather(const int* __restrict__ offm,
                                                    int* __restrict__ gidx){
    int m = blockIdx.x * 256 + threadIdx.x;
    if (m >= MM) return;
    int b = m / Cc, c = m - b * Cc;
    int found = -1;
    for (int t = 0; t < Tt; t++){
        int s = offm[((size_t)(b * Tt + t)) * 2];
        int e = offm[((size_t)(b * Tt + t)) * 2 + 1];
        if (s <= c && c < e){ found = b * Tt + t; break; }
    }
    gidx[m] = found;
}

// ---------------- gather rows of tok (f32) into xg (bf16) -------------------
__global__ __launch_bounds__(256) void gather_convert(const float* __restrict__ tok,
                                                      const int* __restrict__ gidx,
                                                      short* __restrict__ xg){
    size_t idx = (size_t)blockIdx.x * 256 + threadIdx.x;
    if (idx >= (size_t)MM * 192) return;
    int m = (int)(idx / 192), c8 = (int)(idx % 192);
    int g = gidx[m];
    s16x8 o = (s16x8)0;
    if (g >= 0){
        const float* s = tok + (size_t)g * Dd + c8 * 8;
        float4 v0 = *(const float4*)s;
        float4 v1 = *(const float4*)(s + 4);
        o[0] = f2bf(v0.x); o[1] = f2bf(v0.y); o[2] = f2bf(v0.z); o[3] = f2bf(v0.w);
        o[4] = f2bf(v1.x); o[5] = f2bf(v1.y); o[6] = f2bf(v1.z); o[7] = f2bf(v1.w);
    }
    *(s16x8*)(xg + (size_t)m * Dd + c8 * 8) = o;
}

// ---------------- GEMM: C[M,N](bf16) = A[M,K] @ B[N,K]^T + bias ------------
// 128x128x64 tile, 256 thr (2x2 waves, 64x64 each, 4x4 16x16x32 frags).
// global_load_lds(16B) with pre-swizzled global source; XOR chunk swizzle
// (chunk ^= row&7) so ds_read_b128 is bank-optimal. 1D grid: N-tile fastest,
// bijective XCD chunking so same-A-panel blocks share one XCD L2.
__global__ __launch_bounds__(256, 2) void gemm128(const short* __restrict__ A,
                                                  const short* __restrict__ Bw,
                                                  const float* __restrict__ bias1,
                                                  const float* __restrict__ bias2,
                                                  int nb1, int nb2, int halfN,
                                                  short* __restrict__ Cout,
                                                  const int* __restrict__ gidx,
                                                  int K, int NT, int ldc){
    __shared__ short As[128 * 64];
    __shared__ short Bs[128 * 64];
    const int nwg = gridDim.x;
    const int id = blockIdx.x;
    const int q = nwg >> 3, r = nwg & 7;
    const int xcd = id & 7, pos = id >> 3;
    const int wg = (xcd < r ? xcd * (q + 1) : r * (q + 1) + (xcd - r) * q) + pos;
    const int m0 = (wg / NT) * 128, n0 = (wg % NT) * 128;
    const int tid = threadIdx.x, lane = tid & 63, wv = tid >> 6;
    const int wm = wv >> 1, wn = wv & 1;
    const int r16 = lane & 15, kq = lane >> 4;

    f32x4 acc[4][4] = {};

    for (int k0 = 0; k0 < K; k0 += 64){
        #pragma unroll
        for (int i = 0; i < 4; i++){
            int e = (i * 4 + wv) * 64 + lane;
            int row = e >> 3, ch = e & 7;
            int sc = ch ^ (row & 7);
            GLOAD16(A + (size_t)(m0 + row) * K + k0 + (sc << 3),
                    As + (i * 4 + wv) * 512);
        }
        #pragma unroll
        for (int i = 0; i < 4; i++){
            int e = (i * 4 + wv) * 64 + lane;
            int row = e >> 3, ch = e & 7;
            int sc = ch ^ (row & 7);
            GLOAD16(Bw + (size_t)(n0 + row) * K + k0 + (sc << 3),
                    Bs + (i * 4 + wv) * 512);
        }
        __syncthreads();
        #pragma unroll
        for (int ks = 0; ks < 2; ks++){
            s16x8 af[4], bfr[4];
            #pragma unroll
            for (int mt = 0; mt < 4; mt++){
                int row = wm * 64 + mt * 16 + r16;
                int c = (ks * 4 + kq) ^ (row & 7);
                af[mt] = *(const s16x8*)(As + row * 64 + (c << 3));
            }
            #pragma unroll
            for (int nt = 0; nt < 4; nt++){
                int row = wn * 64 + nt * 16 + r16;
                int c = (ks * 4 + kq) ^ (row & 7);
                bfr[nt] = *(const s16x8*)(Bs + row * 64 + (c << 3));
            }
            #pragma unroll
            for (int mt = 0; mt < 4; mt++)
                #pragma unroll
                for (int nt = 0; nt < 4; nt++)
                    acc[mt][nt] = __builtin_amdgcn_mfma_f32_16x16x32_bf16(af[mt], bfr[nt], acc[mt][nt], 0, 0, 0);
        }
        __syncthreads();
    }

    #pragma unroll
    for (int nt = 0; nt < 4; nt++){
        int col = n0 + wn * 64 + nt * 16 + r16;
        float bv;
        if (col < halfN) bv = (col < nb1) ? bias1[col] : 0.f;
        else             bv = (col - halfN < nb2) ? bias2[col - halfN] : 0.f;
        #pragma unroll
        for (int mt = 0; mt < 4; mt++){
            int rowb = m0 + wm * 64 + mt * 16 + kq * 4;
            #pragma unroll
            for (int rr = 0; rr < 4; rr++){
                int row = rowb + rr;
                float v = acc[mt][nt][rr] + bv;
                if (gidx && gidx[row] < 0) v = 0.f;
                Cout[(size_t)row * ldc + col] = f2bf(v);
            }
        }
    }
}

// ---------------- LSTM scan: one (batch, dir) per block --------------------
// xW is the combined [MM, 1152] buffer (f cols 0..575, b cols 576..1151).
__global__ __launch_bounds__(576) void lstm_scan(const short* __restrict__ xW,
                                                 const float* __restrict__ whh_f,
                                                 const float* __restrict__ whh_b,
                                                 const float* __restrict__ h0l,
                                                 const float* __restrict__ c0l,
                                                 short* __restrict__ xout,
                                                 float* __restrict__ hnl,
                                                 float* __restrict__ cnl){
    const int dir = blockIdx.x & 1;
    const int b = blockIdx.x >> 1;
    const int j = threadIdx.x;
    const float* whh = dir ? whh_b : whh_f;

    __shared__ float pre[Gg];
    __shared__ h2 hsh[72];

    h2 wreg[71];
    if (j < Gg){
        const float* wr = whh + (size_t)j * Hh;
        #pragma unroll
        for (int kk = 0; kk < 70; kk++){
            h2 w; w.x = (_Float16)wr[2 * kk]; w.y = (_Float16)wr[2 * kk + 1];
            wreg[kk] = w;
        }
        h2 w; w.x = (_Float16)wr[140]; w.y = (_Float16)0.f;
        wreg[70] = w;
    }

    float hcur = 0.f, ccur = 0.f;
    if (j < Hh){
        hcur = h0l[(size_t)dir * Bb * Hh + b * Hh + j];
        ccur = c0l[(size_t)dir * Bb * Hh + b * Hh + j];
    }
    if (j < 144) ((_Float16*)hsh)[j] = (j < Hh) ? (_Float16)hcur : (_Float16)0.f;
    __syncthreads();

    for (int t = 0; t < Cc; t++){
        int tt = dir ? (Cc - 1 - t) : t;
        if (j < Gg){
            float xw = bf2f(xW[((size_t)b * Cc + tt) * Nc + dir * Gp + j]);
            float acc0 = 0.f, acc1 = 0.f;
            #pragma unroll
            for (int kk = 0; kk < 71; kk++){
                if (kk & 1) acc1 = fdot2(wreg[kk], hsh[kk], acc1);
                else        acc0 = fdot2(wreg[kk], hsh[kk], acc0);
            }
            pre[j] = xw + acc0 + acc1;
        }
        __syncthreads();
        if (j < Hh){
            float gi = sigm(pre[j]);
            float gf = sigm(pre[j + Hh]);
            float gg = tanh_(pre[j + 2 * Hh]);
            float go = sigm(pre[j + 3 * Hh]);
            ccur = gf * ccur + gi * gg;
            hcur = go * tanh_(ccur);
            xout[((size_t)b * Cc + tt) * K2p + dir * Hh + j] = f2bf(hcur);
            ((_Float16*)hsh)[j] = (_Float16)hcur;
        }
        __syncthreads();
    }
    if (j < Hh){
        hnl[(size_t)dir * Bb * Hh + b * Hh + j] = hcur;
        cnl[(size_t)dir * Bb * Hh + b * Hh + j] = ccur;
    }
}

// ---------------- fold head: Wc[2][320] = w2 @ w1 (f32), bc = w2@b1 + b2 ---
__global__ __launch_bounds__(384) void wc_build(const float* __restrict__ w1,
                                                const float* __restrict__ b1,
                                                const float* __restrict__ w2,
                                                const float* __restrict__ b2,
                                                float* __restrict__ Wc){
    int j = threadIdx.x;
    if (j < K2p){
        float a0 = 0.f, a1 = 0.f;
        if (j < 282){
            for (int k = 0; k < 282; k++){
                float w = w1[(size_t)k * 282 + j];
                a0 += w2[k] * w;
                a1 += w2[282 + k] * w;
            }
        }
        Wc[j] = a0;
        Wc[K2p + j] = a1;
    } else if (j < K2p + 2){
        int o = j - K2p;
        float s = b2[o];
        for (int k = 0; k < 282; k++) s += w2[(size_t)o * 282 + k] * b1[k];
        Wc[2 * K2p + o] = s;
    }
}

// ---------------- head matvec: X1,X2 = x4 @ Wc^T + bc ---------------------
__global__ __launch_bounds__(256) void head2_k(const short* __restrict__ x4,
                                               const float* __restrict__ Wc,
                                               float* __restrict__ X1,
                                               float* __restrict__ X2){
    int m = blockIdx.x * 256 + threadIdx.x;
    if (m >= MM) return;
    const short* xr = x4 + (size_t)m * K2p;
    float a0 = 0.f, a1 = 0.f;
    #pragma unroll 4
    for (int c = 0; c < 36; c++){
        s16x8 v = *(const s16x8*)(xr + c * 8);
        #pragma unroll
        for (int u = 0; u < 8; u++){
            float xv = bf2f(v[u]);
            a0 += xv * Wc[c * 8 + u];
            a1 += xv * Wc[K2p + c * 8 + u];
        }
    }
    X1[m] = a0 + Wc[2 * K2p];
    X2[m] = a1 + Wc[2 * K2p + 1];
}

extern "C" void kernel_launch(void* const* d_in, const int* in_sizes, int n_in,
                              void* d_out, int out_size, void* d_ws, size_t ws_size,
                              hipStream_t stream){
    const float* tok     = (const float*)d_in[0];
    const int*   offm    = (const int*)d_in[1];
    const float* h0      = (const float*)d_in[2];
    const float* c0      = (const float*)d_in[3];
    const float* w_lin   = (const float*)d_in[4];
    const float* b_lin   = (const float*)d_in[5];
    const float* w_ih0_f = (const float*)d_in[6];
    const float* w_ih0_b = (const float*)d_in[7];
    const float* w_ih_f  = (const float*)d_in[8];
    const float* w_ih_b  = (const float*)d_in[9];
    const float* w_hh_f  = (const float*)d_in[10];
    const float* w_hh_b  = (const float*)d_in[11];
    const float* b_f     = (const float*)d_in[12];
    const float* b_b     = (const float*)d_in[13];
    const float* w1      = (const float*)d_in[14];
    const float* b1      = (const float*)d_in[15];
    const float* w2      = (const float*)d_in[16];
    const float* b2      = (const float*)d_in[17];

    float* out = (float*)d_out;
    float* oX1 = out;
    float* oX2 = out + MM;
    float* ohn = out + 2 * MM;
    float* ocn = ohn + 8 * Bb * Hh;

    char* ws = (char*)d_ws;
    size_t off = 0;
    auto alloc = [&](size_t bytes) -> void* {
        void* p = ws + off;
        off += (bytes + 255) & ~(size_t)255;
        return p;
    };
    // region1: xg [MM,1536] bf16, later reused as xW [MM,1152] bf16
    short* region1 = (short*)alloc((size_t)MM * Dd * 2);
    // region2: x0 [MM,1536] bf16; later xA at +0, xB at +MM*K2p (x0 dead by then)
    short* region2 = (short*)alloc((size_t)MM * Dd * 2);
    short* wlin16  = (short*)alloc((size_t)Dd * Dd * 2);
    short* w0c     = (short*)alloc((size_t)Nc * Dd * 2);
    short* wc123   = (short*)alloc((size_t)3 * Nc * K2p * 2);
    int*   gidx    = (int*)alloc((size_t)MM * 4);
    float* Wc      = (float*)alloc((size_t)(2 * K2p + 2) * 4);

    short* xg = region1;
    short* xW = region1;
    short* x0 = region2;
    short* xA = region2;
    short* xB = region2 + (size_t)MM * K2p;

    auto cdiv = [](int a, int b){ return (a + b - 1) / b; };

    // weight prep
    convert_pad<<<cdiv(Dd * Dd, 256), 256, 0, stream>>>(w_lin, wlin16, Dd, Dd, Dd, Dd);
    convert_pad<<<cdiv(Gp * Dd, 256), 256, 0, stream>>>(w_ih0_f, w0c, Gg, Dd, Gp, Dd);
    convert_pad<<<cdiv(Gp * Dd, 256), 256, 0, stream>>>(w_ih0_b, w0c + (size_t)Gp * Dd, Gg, Dd, Gp, Dd);
    for (int l = 1; l < 4; l++){
        short* wl = wc123 + (size_t)(l - 1) * Nc * K2p;
        convert_pad<<<cdiv(Gp * K2p, 256), 256, 0, stream>>>(w_ih_f + (size_t)(l - 1) * Gg * 282,
                                                             wl, Gg, 282, Gp, K2p);
        convert_pad<<<cdiv(Gp * K2p, 256), 256, 0, stream>>>(w_ih_b + (size_t)(l - 1) * Gg * 282,
                                                             wl + (size_t)Gp * K2p, Gg, 282, Gp, K2p);
    }
    wc_build<<<1, 384, 0, stream>>>(w1, b1, w2, b2, Wc);

    build_gather<<<cdiv(MM, 256), 256, 0, stream>>>(offm, gidx);
    gather_convert<<<cdiv(MM * 192, 256), 256, 0, stream>>>(tok, gidx, xg);

    // lin: x0 = xg @ w_lin^T + b_lin  (empty rows zeroed via gidx)
    gemm128<<<282 * (Dd / 128), 256, 0, stream>>>(xg, wlin16, b_lin, b_lin,
                                                  Dd, 0, Dd, x0, gidx, Dd, Dd / 128, Dd);

    const short* xin = x0;
    int Kl = Dd;
    short* outbuf[4] = { xA, xB, xA, xB };
    for (int l = 0; l < 4; l++){
        const short* wl = (l == 0) ? w0c : wc123 + (size_t)(l - 1) * Nc * K2p;
        gemm128<<<282 * (Nc / 128), 256, 0, stream>>>(xin, wl,
                                                      b_f + (size_t)l * Gg, b_b + (size_t)l * Gg,
                                                      Gg, Gg, Gp, xW, nullptr, Kl, Nc / 128, Nc);
        lstm_scan<<<512, 576, 0, stream>>>(xW,
                                           w_hh_f + (size_t)l * Gg * Hh, w_hh_b + (size_t)l * Gg * Hh,
                                           h0 + (size_t)(2 * l) * Bb * Hh, c0 + (size_t)(2 * l) * Bb * Hh,
                                           outbuf[l],
                                           ohn + (size_t)(2 * l) * Bb * Hh, ocn + (size_t)(2 * l) * Bb * Hh);
        xin = outbuf[l];
        Kl = K2p;
    }

    head2_k<<<cdiv(MM, 256), 256, 0, stream>>>(xB, Wc, oX1, oX2);
}